// Round 10
// baseline (173.353 us; speedup 1.0000x reference)
//
#include <hip/hip_runtime.h>
#include <stdint.h>

// Problem dims (fixed)
#define BB 2
#define SS 2048
#define DD 1024
#define NH 16
#define HD 64
#define MM 4096   // BB*SS

typedef __bf16 bf16x8 __attribute__((ext_vector_type(8)));
typedef __bf16 bf16x4 __attribute__((ext_vector_type(4)));
typedef float  f32x4  __attribute__((ext_vector_type(4)));

__device__ __forceinline__ unsigned short f2bf(float f) {
    __bf16 h = (__bf16)f;                       // hw v_cvt, RNE
    return __builtin_bit_cast(unsigned short, h);
}

// async global->LDS, 16B per lane. LDS dst must be wave-uniform base + lane*16.
// R5 lesson: this is also the coalescing transform (global side lane-contiguous).
// R6 lesson: 2-wave blocks = same waves/CU as 4-wave at half grid; keep 256-thr attn.
// R7 lesson: XCD swizzle cut FETCH 70->12MB but time flat -> attn is chain-latency-bound.
// R8 lesson: PV software-pipelining regressed 56->67us — attn plateau is structural.
// R9: GEMMs at 8 waves/CU run ~350-450 TF; m97-class rate needs ~16 waves/CU ->
//     512-thread GEMM blocks (this round).
__device__ __forceinline__ void async_cp16(const void* g, const void* l) {
    __builtin_amdgcn_global_load_lds(
        (const __attribute__((address_space(1))) void*)(uintptr_t)g,
        (__attribute__((address_space(3))) void*)(uint32_t)(uintptr_t)l,
        16, 0, 0);
}

__device__ __forceinline__ f32x4 mfma16(bf16x8 a, bf16x8 b, f32x4 c) {
    return __builtin_amdgcn_mfma_f32_16x16x32_bf16(a, b, c, 0, 0, 0);
}

// ---------------- fused prep: H->Hb+Vt (blocks 0..511) and W->bf16 (blocks 512..2047) ----
__global__ __launch_bounds__(256) void k_prep(const float* __restrict__ H,
                                              const float* __restrict__ Wq,
                                              const float* __restrict__ Wk,
                                              const float* __restrict__ Wo,
                                              unsigned short* __restrict__ Hb,
                                              unsigned short* __restrict__ Vt,
                                              unsigned short* __restrict__ Wqb,
                                              unsigned short* __restrict__ Wkb,
                                              unsigned short* __restrict__ Wob) {
    __shared__ float tile[128][68];
    const int bx = blockIdx.x;
    const int t = threadIdx.x;
    if (bx >= 512) {  // weight conversion
        int g = bx - 512;
        const float* src; unsigned short* dst; int base;
        if (g < 512)       { src = Wq; dst = Wqb; base = g; }
        else if (g < 1024) { src = Wk; dst = Wkb; base = g - 512; }
        else               { src = Wo; dst = Wob; base = g - 1024; }
        int i = (base * 256 + t) * 8;
        float4 a = *(const float4*)(src + i);
        float4 b = *(const float4*)(src + i + 4);
        unsigned short o[8];
        o[0] = f2bf(a.x); o[1] = f2bf(a.y); o[2] = f2bf(a.z); o[3] = f2bf(a.w);
        o[4] = f2bf(b.x); o[5] = f2bf(b.y); o[6] = f2bf(b.z); o[7] = f2bf(b.w);
        *(ulonglong2*)(dst + i) = *(ulonglong2*)o;
        return;
    }
    const int sb = bx & 15, h = (bx >> 4) & 15, b = bx >> 8;
    const int col4 = t & 15;
    const int srow0 = t >> 4;
#pragma unroll
    for (int p = 0; p < 8; ++p) {
        int s = p * 16 + srow0;
        float4 v = *(const float4*)(H + (size_t)(b * SS + sb * 128 + s) * DD + h * HD + col4 * 4);
        *(float4*)&tile[s][col4 * 4] = v;
    }
    __syncthreads();
#pragma unroll
    for (int it = 0; it < 4; ++it) {
        int task = it * 256 + t;
        int s = task >> 3;
        int dg = task & 7;
        unsigned short pk[8];
#pragma unroll
        for (int j = 0; j < 8; ++j) pk[j] = f2bf(tile[s][dg * 8 + j]);
        *(ulonglong2*)(Hb + (size_t)(b * SS + sb * 128 + s) * DD + h * HD + dg * 8) = *(ulonglong2*)pk;
    }
#pragma unroll
    for (int it = 0; it < 4; ++it) {
        int task = it * 256 + t;
        int d = task >> 4;
        int sg = task & 15;
        unsigned short pk[8];
#pragma unroll
        for (int j = 0; j < 8; ++j) pk[j] = f2bf(tile[sg * 8 + j][d]);
        *(ulonglong2*)(Vt + (size_t)((b * NH + h) * HD + d) * SS + sb * 128 + sg * 8) = *(ulonglong2*)pk;
    }
}

// ------------- 128x128 MFMA GEMM, 512 threads (8 waves, 2x4), BK=32, dbuf 1-barrier ------
// 32 KB LDS -> qk gets 2 blocks/CU = 16 waves/CU (m97-class occupancy).
// Per iter per thread: 2 cp16 staging; per wave: 6 ds_read_b128 + 8 MFMA.
template <bool BF16OUT>
__device__ __forceinline__ void gemm_body(const unsigned short* __restrict__ A,
                                          const unsigned short* __restrict__ Bt,
                                          const float* __restrict__ bias,
                                          void* __restrict__ Cp, float oscale,
                                          int mBase, int nBase) {
    __shared__ unsigned short lsA[2][128 * 32];
    __shared__ unsigned short lsB[2][128 * 32];
    const int tid = threadIdx.x;           // 0..511
    const int lane = tid & 63;
    const int w = tid >> 6;                // 0..7
    const int wm = w & 1, wn = w >> 1;     // waves 2 (m) x 4 (n)
    const int r = lane & 15, quad = lane >> 4;

    // staging: one 16B chunk per thread per matrix (512 chunks cover 128 rows x 64B)
    {
    }
    int l0 = tid;
    int c0 = l0 ^ ((l0 >> 3) & 7);         // involution on bits 0-2 by bits 3-5
    int row0 = c0 >> 2, kc0 = c0 & 3;
    const unsigned short* gA = A + (size_t)(mBase + row0) * 1024 + kc0 * 8;
    const unsigned short* gB = Bt + (size_t)(nBase + row0) * 1024 + kc0 * 8;
    const uint lOff = (uint)l0 * 8;

    // fragment read offsets (ushort units)
    uint aOff[4], bOff[2];
#pragma unroll
    for (int mt = 0; mt < 4; ++mt) {
        int rowA = wm * 64 + mt * 16 + r;
        int c = rowA * 4 + quad;
        aOff[mt] = (uint)((c ^ ((c >> 3) & 7)) * 8);
    }
#pragma unroll
    for (int nt = 0; nt < 2; ++nt) {
        int rowB = wn * 32 + nt * 16 + r;
        int c = rowB * 4 + quad;
        bOff[nt] = (uint)((c ^ ((c >> 3) & 7)) * 8);
    }

    f32x4 acc[4][2];
#pragma unroll
    for (int i = 0; i < 4; ++i)
#pragma unroll
        for (int j = 0; j < 2; ++j) acc[i][j] = f32x4{0.f, 0.f, 0.f, 0.f};

    auto stage = [&](int buf) {
        async_cp16(gA, &lsA[buf][lOff]); gA += 32;
        async_cp16(gB, &lsB[buf][lOff]); gB += 32;
    };

    stage(0);
    for (int kb = 0; kb < 32; ++kb) {
        const int cur = kb & 1;
        __syncthreads();   // buf[cur] staged; prev reads of buf[cur^1] done
        if (kb + 1 < 32) stage(cur ^ 1);

        bf16x8 af[4], bf[2];
#pragma unroll
        for (int mt = 0; mt < 4; ++mt) af[mt] = *(const bf16x8*)&lsA[cur][aOff[mt]];
#pragma unroll
        for (int nt = 0; nt < 2; ++nt) bf[nt] = *(const bf16x8*)&lsB[cur][bOff[nt]];
#pragma unroll
        for (int mt = 0; mt < 4; ++mt)
#pragma unroll
            for (int nt = 0; nt < 2; ++nt)
                acc[mt][nt] = mfma16(af[mt], bf[nt], acc[mt][nt]);
    }

    float bv[2];
#pragma unroll
    for (int nt = 0; nt < 2; ++nt) bv[nt] = bias[nBase + wn * 32 + nt * 16 + r];
#pragma unroll
    for (int mt = 0; mt < 4; ++mt)
#pragma unroll
        for (int nt = 0; nt < 2; ++nt) {
            int colg = nBase + wn * 32 + nt * 16 + r;
#pragma unroll
            for (int reg = 0; reg < 4; ++reg) {
                int rowg = mBase + wm * 64 + mt * 16 + quad * 4 + reg;
                float v = (acc[mt][nt][reg] + bv[nt]) * oscale;
                if (BF16OUT)
                    ((unsigned short*)Cp)[(size_t)rowg * 1024 + colg] = f2bf(v);
                else
                    ((float*)Cp)[(size_t)rowg * 1024 + colg] = v;
            }
        }
}

#define QSCALE 0.1803368801111137f   // (1/sqrt(64)) * log2(e)

// 512 blocks x 512 thr; id = x*64 + yp -> all 8 n-blocks of one A-strip share id%8 (XCD).
__global__ __launch_bounds__(512) void k_gemm_qk(const unsigned short* __restrict__ Hb,
                                                 const unsigned short* __restrict__ Wqb,
                                                 const unsigned short* __restrict__ Wkb,
                                                 const float* __restrict__ bq,
                                                 const float* __restrict__ bk,
                                                 unsigned short* __restrict__ Q,
                                                 unsigned short* __restrict__ K) {
    const int id = blockIdx.x;
    const int x = id >> 6, yp = id & 63;
    const int z = yp >> 5, y = yp & 31;
    const unsigned short* Bt = z ? Wkb : Wqb;
    const float* bias = z ? bk : bq;
    unsigned short* C = z ? K : Q;
    float os = z ? 1.0f : QSCALE;
    gemm_body<true>(Hb, Bt, bias, C, os, y * 128, x * 128);
}

// 256 blocks x 512 thr (1 block/CU, 8 waves); id = x*32 + y -> A-strip grouping for XCD.
__global__ __launch_bounds__(512) void k_gemm_out(const unsigned short* __restrict__ Ctx,
                                                  const unsigned short* __restrict__ Wob,
                                                  const float* __restrict__ bo,
                                                  float* __restrict__ Out) {
    const int id = blockIdx.x;
    const int x = id >> 5, y = id & 31;
    gemm_body<false>(Ctx, Wob, bo, Out, 1.0f, y * 128, x * 128);
}

// ---------------- flash attention: KT=128 k-tiles (16 barriers), XCD-swizzled grid ----------
// R7 structure, measured 56.4-58.5us — best of 6 attn variants; unchanged.
__global__ __launch_bounds__(256) void k_attn(const unsigned short* __restrict__ Q,
                                              const unsigned short* __restrict__ K,
                                              const unsigned short* __restrict__ Vt,
                                              unsigned short* __restrict__ Ctx) {
    __shared__ unsigned short lsK[2][128 * 64];  // [buf][half*64 + sigma-row][d]
    __shared__ unsigned short lsV[2][128 * 64];  // [buf][half*64*64 + d*64 + kpos]
    __shared__ unsigned short lsP[4 * 2048];     // per-wave [q32][k64]
    const int tid = threadIdx.x;
    const int lane = tid & 63;
    const int w = tid >> 6;
    const int r = lane & 15, quad = lane >> 4;
    const int id = blockIdx.x;
    const int xcd = id & 7, j = id >> 3;
    const int hb = xcd + 8 * (j & 3);
    const int qb = j >> 2;
    const int h = hb & 15, b = hb >> 4;

    bf16x8 aq[2][2];
#pragma unroll
    for (int sub = 0; sub < 2; ++sub) {
        const int qrow = qb * 128 + w * 32 + sub * 16 + r;
        const size_t qoff = (size_t)(b * SS + qrow) * DD + h * HD;
        aq[sub][0] = *(const bf16x8*)(Q + qoff + quad * 8);
        aq[sub][1] = *(const bf16x8*)(Q + qoff + 32 + quad * 8);
    }

    f32x4 accO[2][4];
#pragma unroll
    for (int sub = 0; sub < 2; ++sub)
#pragma unroll
        for (int nt = 0; nt < 4; ++nt) accO[sub][nt] = f32x4{0.f, 0.f, 0.f, 0.f};
    float lsum[2][4] = {{0.f, 0.f, 0.f, 0.f}, {0.f, 0.f, 0.f, 0.f}};

    const unsigned short* gK[4]; const unsigned short* gV[4]; uint lO[4];
#pragma unroll
    for (int t = 0; t < 4; ++t) {
        int l = t * 256 + tid;
        int c = l ^ ((l >> 3) & 7);
        int half = c >> 9, kc = c & 7;
        int rr = (c >> 3) & 63;
        int srow = half * 64 + 4 * (rr & 15) + (rr >> 4);   // sigma within 64-half
        gK[t] = K + (size_t)(b * SS + srow) * DD + h * HD + kc * 8;
        gV[t] = Vt + (size_t)((b * NH + h) * HD + rr) * SS + half * 64 + kc * 8;
        lO[t] = l * 8;
    }
    uint off[2][4];
#pragma unroll
    for (int t = 0; t < 2; ++t)
#pragma unroll
        for (int nt = 0; nt < 4; ++nt) {
            int rowX = nt * 16 + r;
            int c = rowX * 8 + t * 4 + quad;
            off[t][nt] = (uint)((c ^ ((c >> 3) & 7)) * 8);
        }
    uint pw[4], pr[2];
#pragma unroll
    for (int reg = 0; reg < 4; ++reg) {
        int prow = quad * 4 + reg;
        pw[reg] = (uint)(prow * 64 + ((r >> 1) ^ (prow & 7)) * 8 + (r & 1) * 4);
    }
#pragma unroll
    for (int t = 0; t < 2; ++t)
        pr[t] = (uint)(r * 64 + ((4 * t + quad) ^ (r & 7)) * 8);
    unsigned short* Pw = lsP + w * 2048;

    auto stage = [&](int buf) {
#pragma unroll
        for (int t = 0; t < 4; ++t) {
            async_cp16(gK[t], &lsK[buf][lO[t]]); gK[t] += 128 * DD;
            async_cp16(gV[t], &lsV[buf][lO[t]]); gV[t] += 128;
        }
    };

    stage(0);
    for (int kt = 0; kt < 16; ++kt) {
        const int cur = kt & 1;
        __syncthreads();
        if (kt + 1 < 16) stage(cur ^ 1);

#pragma unroll
        for (int half = 0; half < 2; ++half) {
            const uint ho = (uint)half * 4096;

            f32x4 s[2][4];
#pragma unroll
            for (int sub = 0; sub < 2; ++sub)
#pragma unroll
                for (int nt = 0; nt < 4; ++nt) s[sub][nt] = f32x4{0.f, 0.f, 0.f, 0.f};
#pragma unroll
            for (int t = 0; t < 2; ++t)
#pragma unroll
                for (int nt = 0; nt < 4; ++nt) {
                    bf16x8 bk = *(const bf16x8*)&lsK[cur][ho + off[t][nt]];
                    s[0][nt] = mfma16(aq[0][t], bk, s[0][nt]);
                    s[1][nt] = mfma16(aq[1][t], bk, s[1][nt]);
                }

#pragma unroll
            for (int sub = 0; sub < 2; ++sub)
#pragma unroll
                for (int reg = 0; reg < 4; ++reg) {
                    float p0 = __builtin_amdgcn_exp2f(s[sub][0][reg]);
                    float p1 = __builtin_amdgcn_exp2f(s[sub][1][reg]);
                    float p2 = __builtin_amdgcn_exp2f(s[sub][2][reg]);
                    float p3 = __builtin_amdgcn_exp2f(s[sub][3][reg]);
                    lsum[sub][reg] += (p0 + p1) + (p2 + p3);
                    bf16x4 pk = {(__bf16)p0, (__bf16)p1, (__bf16)p2, (__bf16)p3};
                    *(bf16x4*)&Pw[sub * 1024 + pw[reg]] = pk;
                }

#pragma unroll
            for (int t = 0; t < 2; ++t) {
                bf16x8 ap0 = *(const bf16x8*)&Pw[pr[t]];
                bf16x8 ap1 = *(const bf16x8*)&Pw[1024 + pr[t]];
#pragma unroll
                for (int nt = 0; nt < 4; ++nt) {
                    bf16x8 bv = *(const bf16x8*)&lsV[cur][ho + off[t][nt]];
                    accO[0][nt] = mfma16(ap0, bv, accO[0][nt]);
                    accO[1][nt] = mfma16(ap1, bv, accO[1][nt]);
                }
            }
        }
    }

#pragma unroll
    for (int sub = 0; sub < 2; ++sub) {
        float linv[4];
#pragma unroll
        for (int reg = 0; reg < 4; ++reg) {
            float l = lsum[sub][reg];
            l += __shfl_xor(l, 1);
            l += __shfl_xor(l, 2);
            l += __shfl_xor(l, 4);
            l += __shfl_xor(l, 8);
            linv[reg] = 1.0f / l;
        }
#pragma unroll
        for (int nt = 0; nt < 4; ++nt) {
            int d = nt * 16 + r;
#pragma unroll
            for (int reg = 0; reg < 4; ++reg) {
                int qr = qb * 128 + w * 32 + sub * 16 + quad * 4 + reg;
                Ctx[(size_t)(b * SS + qr) * DD + h * HD + d] = f2bf(accO[sub][nt][reg] * linv[reg]);
            }
        }
    }
}

extern "C" void kernel_launch(void* const* d_in, const int* in_sizes, int n_in,
                              void* d_out, int out_size, void* d_ws, size_t ws_size,
                              hipStream_t stream) {
    (void)in_sizes; (void)n_in; (void)out_size; (void)ws_size;
    const float* H  = (const float*)d_in[0];
    const float* Wq = (const float*)d_in[1];
    const float* bq = (const float*)d_in[2];
    const float* Wk = (const float*)d_in[3];
    const float* bk = (const float*)d_in[4];
    const float* Wo = (const float*)d_in[5];
    const float* bo = (const float*)d_in[6];
    float* Out = (float*)d_out;

    char* ws = (char*)d_ws;
    unsigned short* Hb  = (unsigned short*)(ws);                 // 8 MB
    unsigned short* Qb  = (unsigned short*)(ws + 8388608);       // 8 MB (pre-scaled)
    unsigned short* Kb  = (unsigned short*)(ws + 16777216);      // 8 MB
    unsigned short* Ctx = (unsigned short*)(ws + 25165824);      // 8 MB
    unsigned short* Vt  = (unsigned short*)(ws + 33554432);      // 8 MB
    unsigned short* Wqb = (unsigned short*)(ws + 41943040);      // 2 MB
    unsigned short* Wkb = (unsigned short*)(ws + 44040192);      // 2 MB
    unsigned short* Wob = (unsigned short*)(ws + 46137344);      // 2 MB

    k_prep<<<dim3(2048), dim3(256), 0, stream>>>(H, Wq, Wk, Wo, Hb, Vt, Wqb, Wkb, Wob);
    k_gemm_qk<<<dim3(512), dim3(512), 0, stream>>>(Hb, Wqb, Wkb, bq, bk, Qb, Kb);
    k_attn<<<dim3(512), dim3(256), 0, stream>>>(Qb, Kb, Vt, Ctx);
    k_gemm_out<<<dim3(256), dim3(512), 0, stream>>>(Ctx, Wob, bo, Out);
}